// Round 1
// baseline (91.679 us; speedup 1.0000x reference)
//
#include <hip/hip_runtime.h>

// CubeLens: radial lens deflection + bilinear gather + 4x4 avg pool.
// C=64, NS=256, NL=192, UPS=4. Output (64,192,192) fp32.
//
// Mapping: thread = (output pixel, 8-channel group). grid=(144,8), block=256.
//   - geometry (sqrt + 2 div) computed once per 8 channels
//   - bilinear weights shared across the 8-channel inner loop
//   - adjacent lanes = adjacent lx -> tap addresses nearly contiguous
//   - ops mirror the jax reference bit-for-bit in fp32 (no fast-math tricks)

#define NSRC 256
#define NLENS 192
#define CGRP 8

__global__ __launch_bounds__(256) void cubelens_kernel(
    const float* __restrict__ src,      // (64, 256, 256)
    const float* __restrict__ theta_p,  // (1,)
    float* __restrict__ out)            // (64, 192, 192)
{
    const float tE = theta_p[0];
    const int pix = blockIdx.x * 256 + threadIdx.x;   // 0 .. 36863
    const int c0  = blockIdx.y * CGRP;
    const int lx  = pix % NLENS;
    const int ly  = pix / NLENS;

    float acc[CGRP];
#pragma unroll
    for (int c = 0; c < CGRP; ++c) acc[c] = 0.0f;

    const float* __restrict__ srcg = src + (size_t)c0 * (NSRC * NSRC);

#pragma unroll
    for (int uy = 0; uy < 4; ++uy) {
        const int gy = ly * 4 + uy;
        const float thy = ((float)gy - 383.5f) * 0.01f;
#pragma unroll
        for (int ux = 0; ux < 4; ++ux) {
            const int gx = lx * 4 + ux;
            const float thx = ((float)gx - 383.5f) * 0.01f;

            const float r  = sqrtf(thx * thx + thy * thy) + 1e-8f;
            const float bx = thx - (tE * thx) / r;
            const float by = thy - (tE * thy) / r;
            const float fx = bx / 0.02f + 127.5f;
            const float fy = by / 0.02f + 127.5f;

            const bool inb = (fx >= 0.0f) & (fx <= 255.0f) &
                             (fy >= 0.0f) & (fy <= 255.0f);
            if (!inb) continue;

            int x0 = (int)floorf(fx); x0 = min(max(x0, 0), 254);
            int y0 = (int)floorf(fy); y0 = min(max(y0, 0), 254);
            const float wx = fminf(fmaxf(fx - (float)x0, 0.0f), 1.0f);
            const float wy = fminf(fmaxf(fy - (float)y0, 0.0f), 1.0f);

            const float w00 = (1.0f - wy) * (1.0f - wx);
            const float w01 = (1.0f - wy) * wx;
            const float w10 = wy * (1.0f - wx);
            const float w11 = wy * wx;

            const float* __restrict__ p = srcg + y0 * NSRC + x0;
#pragma unroll
            for (int c = 0; c < CGRP; ++c) {
                const float* __restrict__ pc = p + c * (NSRC * NSRC);
                acc[c] += w00 * pc[0] + w01 * pc[1]
                        + w10 * pc[NSRC] + w11 * pc[NSRC + 1];
            }
        }
    }

#pragma unroll
    for (int c = 0; c < CGRP; ++c)
        out[(size_t)(c0 + c) * (NLENS * NLENS) + pix] = acc[c] * 0.0625f;
}

extern "C" void kernel_launch(void* const* d_in, const int* in_sizes, int n_in,
                              void* d_out, int out_size, void* d_ws, size_t ws_size,
                              hipStream_t stream) {
    const float* src   = (const float*)d_in[0];
    const float* theta = (const float*)d_in[1];
    float* out = (float*)d_out;

    dim3 grid(NLENS * NLENS / 256, 64 / CGRP);  // (144, 8)
    dim3 block(256);
    cubelens_kernel<<<grid, block, 0, stream>>>(src, theta, out);
}

// Round 2
// 46.561 us; speedup vs baseline: 1.9690x; 1.9690x over previous
//
#include <hip/hip_runtime.h>

// CubeLens: radial lens deflection + bilinear gather + 4x4 avg pool.
// C=64, NS=256, NL=192, UPS=4. Output (64,192,192) fp32.
//
// R2 strategy:
//   k1: transpose src (64,256,256) -> ws (256,256,64)  [channel-last]
//   k2: per block: 16 output pixels. Phase1: 256 thr = 16px x 16taps geometry
//       into LDS. Phase2: thr=(px, c4grp): 4 float4 corner loads per tap,
//       fully coalesced (16 lanes = 64 consecutive channels = 256B).
//       XCD swizzle: blockIdx%8 = XCD (round-robin dispatch), each XCD gets a
//       contiguous 24-row pixel band -> ~3.2MB source slab fits 4MiB L2.
//       Phase3: LDS repack -> 64B-aligned coalesced stores.

#define NSRC 256
#define NLENS 192
#define NPIX (NLENS * NLENS)     // 36864
#define CSZ  64
#define PXB  16                  // pixels per block
#define NBLK (NPIX / PXB)        // 2304 blocks (divisible by 8)

// ---------------- fallback (round-1 kernel, used only if ws too small) ------
__global__ __launch_bounds__(256) void cubelens_fallback(
    const float* __restrict__ src, const float* __restrict__ theta_p,
    float* __restrict__ out)
{
    const float tE = theta_p[0];
    const int pix = blockIdx.x * 256 + threadIdx.x;
    const int c0  = blockIdx.y * 8;
    const int lx  = pix % NLENS;
    const int ly  = pix / NLENS;
    float acc[8];
#pragma unroll
    for (int c = 0; c < 8; ++c) acc[c] = 0.0f;
    const float* __restrict__ srcg = src + (size_t)c0 * (NSRC * NSRC);
#pragma unroll
    for (int uy = 0; uy < 4; ++uy) {
        const float thy = ((float)(ly * 4 + uy) - 383.5f) * 0.01f;
#pragma unroll
        for (int ux = 0; ux < 4; ++ux) {
            const float thx = ((float)(lx * 4 + ux) - 383.5f) * 0.01f;
            const float r  = sqrtf(thx * thx + thy * thy) + 1e-8f;
            const float fx = (thx - (tE * thx) / r) / 0.02f + 127.5f;
            const float fy = (thy - (tE * thy) / r) / 0.02f + 127.5f;
            const bool inb = (fx >= 0.0f) & (fx <= 255.0f) &
                             (fy >= 0.0f) & (fy <= 255.0f);
            if (!inb) continue;
            int x0 = min(max((int)floorf(fx), 0), 254);
            int y0 = min(max((int)floorf(fy), 0), 254);
            const float wx = fminf(fmaxf(fx - (float)x0, 0.0f), 1.0f);
            const float wy = fminf(fmaxf(fy - (float)y0, 0.0f), 1.0f);
            const float w00 = (1.0f - wy) * (1.0f - wx);
            const float w01 = (1.0f - wy) * wx;
            const float w10 = wy * (1.0f - wx);
            const float w11 = wy * wx;
            const float* __restrict__ p = srcg + y0 * NSRC + x0;
#pragma unroll
            for (int c = 0; c < 8; ++c) {
                const float* __restrict__ pc = p + c * (NSRC * NSRC);
                acc[c] += w00 * pc[0] + w01 * pc[1]
                        + w10 * pc[NSRC] + w11 * pc[NSRC + 1];
            }
        }
    }
#pragma unroll
    for (int c = 0; c < 8; ++c)
        out[(size_t)(c0 + c) * NPIX + pix] = acc[c] * 0.0625f;
}

// ---------------- k1: transpose (c, p) -> (p, c), p = y*256+x ---------------
__global__ __launch_bounds__(256) void transpose_kernel(
    const float* __restrict__ src, float* __restrict__ ws)
{
    __shared__ float tile[CSZ][65];
    const int p0 = blockIdx.x * 64;
    const int t  = threadIdx.x;
    {
        const int pp = t & 63, c4 = t >> 6;
#pragma unroll
        for (int i = 0; i < 16; ++i) {
            const int c = c4 * 16 + i;
            tile[c][pp] = src[(size_t)c * (NSRC * NSRC) + p0 + pp];
        }
    }
    __syncthreads();
    {
        const int cc = t & 63, q = t >> 6;
#pragma unroll
        for (int j = 0; j < 16; ++j) {
            const int pp = q * 16 + j;
            ws[(size_t)(p0 + pp) * CSZ + cc] = tile[cc][pp];
        }
    }
}

// ---------------- k2: lens gather from channel-last ws ----------------------
__global__ __launch_bounds__(256) void cubelens_main(
    const float* __restrict__ ws,       // (256,256,64)
    const float* __restrict__ theta_p,
    float* __restrict__ out)            // (64,192,192)
{
    __shared__ int   gbase[PXB][16];
    __shared__ float gw[PXB][16][4];
    __shared__ int   ginb[PXB][16];
    __shared__ float smemO[CSZ][PXB + 1];   // padded: 2-way max on write (free)

    const float tE = theta_p[0];

    // XCD swizzle: round-robin dispatch -> give XCD (b%8) a contiguous band
    const int b = blockIdx.x;
    const int pixblock = (b & 7) * (NBLK / 8) + (b >> 3);
    const int p0 = pixblock * PXB;
    const int t = threadIdx.x;

    // phase 1: geometry, thread = (pixel_in_block, tap)
    {
        const int pi = t >> 4, tap = t & 15;
        const int p  = p0 + pi;
        const int lx = p % NLENS, ly = p / NLENS;
        const int uy = tap >> 2, ux = tap & 3;
        const float thy = ((float)(ly * 4 + uy) - 383.5f) * 0.01f;
        const float thx = ((float)(lx * 4 + ux) - 383.5f) * 0.01f;
        const float r  = sqrtf(thx * thx + thy * thy) + 1e-8f;
        const float fx = (thx - (tE * thx) / r) / 0.02f + 127.5f;
        const float fy = (thy - (tE * thy) / r) / 0.02f + 127.5f;
        const bool inb = (fx >= 0.0f) & (fx <= 255.0f) &
                         (fy >= 0.0f) & (fy <= 255.0f);
        int x0 = min(max((int)floorf(fx), 0), 254);
        int y0 = min(max((int)floorf(fy), 0), 254);
        const float wx = fminf(fmaxf(fx - (float)x0, 0.0f), 1.0f);
        const float wy = fminf(fmaxf(fy - (float)y0, 0.0f), 1.0f);
        gbase[pi][tap]  = (y0 * NSRC + x0) * CSZ;
        gw[pi][tap][0]  = (1.0f - wy) * (1.0f - wx);
        gw[pi][tap][1]  = (1.0f - wy) * wx;
        gw[pi][tap][2]  = wy * (1.0f - wx);
        gw[pi][tap][3]  = wy * wx;
        ginb[pi][tap]   = inb ? 1 : 0;
    }
    __syncthreads();

    // phase 2: gather, thread = (pixel_in_block, c4) ; c4 -> channels 4c4..4c4+3
    {
        const int pi = t >> 4, c4 = t & 15;
        float4 acc = make_float4(0.f, 0.f, 0.f, 0.f);
#pragma unroll
        for (int tap = 0; tap < 16; ++tap) {
            if (!ginb[pi][tap]) continue;
            const int base = gbase[pi][tap] + c4 * 4;
            const float4 v00 = *(const float4*)(ws + base);
            const float4 v01 = *(const float4*)(ws + base + CSZ);
            const float4 v10 = *(const float4*)(ws + base + NSRC * CSZ);
            const float4 v11 = *(const float4*)(ws + base + NSRC * CSZ + CSZ);
            const float w00 = gw[pi][tap][0];
            const float w01 = gw[pi][tap][1];
            const float w10 = gw[pi][tap][2];
            const float w11 = gw[pi][tap][3];
            acc.x += w00 * v00.x + w01 * v01.x + w10 * v10.x + w11 * v11.x;
            acc.y += w00 * v00.y + w01 * v01.y + w10 * v10.y + w11 * v11.y;
            acc.z += w00 * v00.z + w01 * v01.z + w10 * v10.z + w11 * v11.z;
            acc.w += w00 * v00.w + w01 * v01.w + w10 * v10.w + w11 * v11.w;
        }
        smemO[c4 * 4 + 0][pi] = acc.x;
        smemO[c4 * 4 + 1][pi] = acc.y;
        smemO[c4 * 4 + 2][pi] = acc.z;
        smemO[c4 * 4 + 3][pi] = acc.w;
    }
    __syncthreads();

    // phase 3: coalesced stores. 64B-aligned 16-float clusters per channel.
    {
        const int pix = t & 15;
#pragma unroll
        for (int it = 0; it < 4; ++it) {
            const int c = (t >> 4) + 16 * it;
            out[(size_t)c * NPIX + p0 + pix] = smemO[c][pix] * 0.0625f;
        }
    }
}

extern "C" void kernel_launch(void* const* d_in, const int* in_sizes, int n_in,
                              void* d_out, int out_size, void* d_ws, size_t ws_size,
                              hipStream_t stream) {
    const float* src   = (const float*)d_in[0];
    const float* theta = (const float*)d_in[1];
    float* out = (float*)d_out;

    const size_t need = (size_t)CSZ * NSRC * NSRC * sizeof(float);  // 16.78 MB
    if (ws_size >= need) {
        float* ws = (float*)d_ws;
        transpose_kernel<<<dim3(NSRC * NSRC / 64), dim3(256), 0, stream>>>(src, ws);
        cubelens_main<<<dim3(NBLK), dim3(256), 0, stream>>>(ws, theta, out);
    } else {
        cubelens_fallback<<<dim3(NPIX / 256, 8), dim3(256), 0, stream>>>(src, theta, out);
    }
}

// Round 3
// 37.856 us; speedup vs baseline: 2.4218x; 1.2300x over previous
//
#include <hip/hip_runtime.h>

// CubeLens: radial lens deflection + bilinear gather + 4x4 avg pool.
// C=64, NS=256, NL=192, UPS=4. Output (64,192,192) fp32.
//
// R3 strategy:
//   k1: transpose src (64,256,256) -> ws (256,256,64), float4 both sides.
//   k2: block = 16 output pixels x 64 channels. 16-lane group per pixel.
//       1a: lane=tap: geometry (16 taps = 4x4 upsample grid).
//       1b: shfl_xor min/max of tap footprint over the group.
//       patch mode (span<=2, ~all pixels): lane=corner of 4x4 patch,
//         accumulate the 16 taps' bilinear weights per corner via shfl
//         broadcast; then lane=c4: gather each nonzero corner ONCE
//         (~9 float4 loads vs 64 per-tap loads). Weight skip is
//         group-uniform. Fallback per-tap path for wide-span pixels
//         (lens-center magnification), also via shfl (branch is
//         group-uniform so all shfl sources are active).
//       Output via LDS repack -> float4 coalesced stores.
//       XCD swizzle: blockIdx%8 -> contiguous band per XCD (L2 fit ~3MB).

#define NSRC 256
#define NLENS 192
#define NPIX (NLENS * NLENS)     // 36864
#define CSZ  64
#define PXB  16
#define NBLK (NPIX / PXB)        // 2304, divisible by 8

// ---------------- fallback (round-1 kernel, used only if ws too small) ------
__global__ __launch_bounds__(256) void cubelens_fallback(
    const float* __restrict__ src, const float* __restrict__ theta_p,
    float* __restrict__ out)
{
    const float tE = theta_p[0];
    const int pix = blockIdx.x * 256 + threadIdx.x;
    const int c0  = blockIdx.y * 8;
    const int lx  = pix % NLENS;
    const int ly  = pix / NLENS;
    float acc[8];
#pragma unroll
    for (int c = 0; c < 8; ++c) acc[c] = 0.0f;
    const float* __restrict__ srcg = src + (size_t)c0 * (NSRC * NSRC);
#pragma unroll
    for (int uy = 0; uy < 4; ++uy) {
        const float thy = ((float)(ly * 4 + uy) - 383.5f) * 0.01f;
#pragma unroll
        for (int ux = 0; ux < 4; ++ux) {
            const float thx = ((float)(lx * 4 + ux) - 383.5f) * 0.01f;
            const float r  = sqrtf(thx * thx + thy * thy) + 1e-8f;
            const float fx = (thx - (tE * thx) / r) / 0.02f + 127.5f;
            const float fy = (thy - (tE * thy) / r) / 0.02f + 127.5f;
            const bool inb = (fx >= 0.0f) & (fx <= 255.0f) &
                             (fy >= 0.0f) & (fy <= 255.0f);
            if (!inb) continue;
            int x0 = min(max((int)floorf(fx), 0), 254);
            int y0 = min(max((int)floorf(fy), 0), 254);
            const float wx = fminf(fmaxf(fx - (float)x0, 0.0f), 1.0f);
            const float wy = fminf(fmaxf(fy - (float)y0, 0.0f), 1.0f);
            const float w00 = (1.0f - wy) * (1.0f - wx);
            const float w01 = (1.0f - wy) * wx;
            const float w10 = wy * (1.0f - wx);
            const float w11 = wy * wx;
            const float* __restrict__ p = srcg + y0 * NSRC + x0;
#pragma unroll
            for (int c = 0; c < 8; ++c) {
                const float* __restrict__ pc = p + c * (NSRC * NSRC);
                acc[c] += w00 * pc[0] + w01 * pc[1]
                        + w10 * pc[NSRC] + w11 * pc[NSRC + 1];
            }
        }
    }
#pragma unroll
    for (int c = 0; c < 8; ++c)
        out[(size_t)(c0 + c) * NPIX + pix] = acc[c] * 0.0625f;
}

// ---------------- k1: transpose (c, p) -> (p, c), float4 both sides ---------
__global__ __launch_bounds__(256) void transpose_kernel(
    const float* __restrict__ src, float* __restrict__ ws)
{
    __shared__ float tile[CSZ][65];
    const int p0 = blockIdx.x * 64;
    const int t  = threadIdx.x;
    {
        const int crow = t >> 4;            // 0..15
        const int px4  = (t & 15) * 4;      // 0..60
#pragma unroll
        for (int i = 0; i < 4; ++i) {
            const int c = crow + 16 * i;
            const float4 v = *(const float4*)(src + (size_t)c * (NSRC * NSRC) + p0 + px4);
            tile[c][px4 + 0] = v.x; tile[c][px4 + 1] = v.y;
            tile[c][px4 + 2] = v.z; tile[c][px4 + 3] = v.w;
        }
    }
    __syncthreads();
    {
        const int prow = t >> 4;            // 0..15
        const int c4   = (t & 15) * 4;      // 0..60
#pragma unroll
        for (int i = 0; i < 4; ++i) {
            const int p = prow + 16 * i;
            float4 v;
            v.x = tile[c4 + 0][p]; v.y = tile[c4 + 1][p];
            v.z = tile[c4 + 2][p]; v.w = tile[c4 + 3][p];
            *(float4*)(ws + (size_t)(p0 + p) * CSZ + c4) = v;
        }
    }
}

// ---------------- k2: lens gather, unique-corner patch mode -----------------
__global__ __launch_bounds__(256) void cubelens_main(
    const float* __restrict__ ws,       // (256,256,64)
    const float* __restrict__ theta_p,
    float* __restrict__ out)            // (64,192,192)
{
    __shared__ float smemO[CSZ][PXB + 1];

    const float tE = theta_p[0];
    const int b = blockIdx.x;
    const int pixblock = (b & 7) * (NBLK / 8) + (b >> 3);   // XCD swizzle
    const int p0 = pixblock * PXB;
    const int t  = threadIdx.x;
    const int pi  = t >> 4;      // pixel in block (16-lane group id)
    const int sub = t & 15;      // tap in 1a, corner in 1c, c4 in phase 2

    // --- 1a: geometry for tap = sub (4x4 upsample grid of this pixel) ---
    const int p  = p0 + pi;
    const int lx = p % NLENS, ly = p / NLENS;
    const float thy = ((float)(ly * 4 + (sub >> 2)) - 383.5f) * 0.01f;
    const float thx = ((float)(lx * 4 + (sub & 3))  - 383.5f) * 0.01f;
    const float r  = sqrtf(thx * thx + thy * thy) + 1e-8f;
    const float fx = (thx - (tE * thx) / r) / 0.02f + 127.5f;
    const float fy = (thy - (tE * thy) / r) / 0.02f + 127.5f;
    const bool inb = (fx >= 0.0f) & (fx <= 255.0f) &
                     (fy >= 0.0f) & (fy <= 255.0f);
    int x0 = min(max((int)floorf(fx), 0), 254);
    int y0 = min(max((int)floorf(fy), 0), 254);
    const float wx = fminf(fmaxf(fx - (float)x0, 0.0f), 1.0f);
    const float wy = fminf(fmaxf(fy - (float)y0, 0.0f), 1.0f);
    if (!inb) { x0 = -100000; y0 = -100000; }   // never matches a corner

    // --- 1b: footprint min/max over the 16-lane pixel group ---
    int mnx = inb ? x0 : 0x0FFFFFFF, mny = inb ? y0 : 0x0FFFFFFF;
    int mxx = x0, mxy = y0;                      // -100000 never wins max
#pragma unroll
    for (int off = 1; off < 16; off <<= 1) {
        mnx = min(mnx, __shfl_xor(mnx, off, 16));
        mny = min(mny, __shfl_xor(mny, off, 16));
        mxx = max(mxx, __shfl_xor(mxx, off, 16));
        mxy = max(mxy, __shfl_xor(mxy, off, 16));
    }
    const bool patchmode = (mxx - mnx <= 2) && (mxy - mny <= 2);
    const int bx0 = max(min(mnx, 252), 0);
    const int by0 = max(min(mny, 252), 0);

    // --- 1c (patch mode): corner = sub; accumulate tap weights per corner ---
    float myw = 0.0f;
    if (patchmode) {                // uniform per 16-lane group -> shfl safe
        const int cx = sub & 3, cy = sub >> 2;
#pragma unroll
        for (int j = 0; j < 16; ++j) {
            const int   tx0 = __shfl(x0, j, 16);
            const int   ty0 = __shfl(y0, j, 16);
            const float twx = __shfl(wx, j, 16);
            const float twy = __shfl(wy, j, 16);
            const int ax = cx - (tx0 - bx0);
            const int ay = cy - (ty0 - by0);
            if (((unsigned)ax <= 1u) & ((unsigned)ay <= 1u))
                myw += (ax ? twx : 1.0f - twx) * (ay ? twy : 1.0f - twy);
        }
    }

    // --- phase 2: gather. lane = (pixel, c4); channels 4*sub .. 4*sub+3 ---
    const int c4o = sub * 4;
    float4 acc = make_float4(0.f, 0.f, 0.f, 0.f);
    if (patchmode) {
        const float* __restrict__ basep =
            ws + (size_t)(by0 * NSRC + bx0) * CSZ + c4o;
#pragma unroll
        for (int cn = 0; cn < 16; ++cn) {
            const float w = __shfl(myw, cn, 16);   // corner cn's weight
            if (w != 0.0f) {                       // uniform per group
                const float4 v = *(const float4*)
                    (basep + ((cn >> 2) * NSRC + (cn & 3)) * CSZ);
                acc.x += w * v.x; acc.y += w * v.y;
                acc.z += w * v.z; acc.w += w * v.w;
            }
        }
    } else {
        // rare wide-span pixels (lens-center magnification): per-tap path
        for (int j = 0; j < 16; ++j) {
            const int   tx0 = __shfl(x0, j, 16);
            const int   ty0 = __shfl(y0, j, 16);
            const float twx = __shfl(wx, j, 16);
            const float twy = __shfl(wy, j, 16);
            if (tx0 >= 0) {
                const float* __restrict__ pp =
                    ws + (size_t)(ty0 * NSRC + tx0) * CSZ + c4o;
                const float4 v00 = *(const float4*)(pp);
                const float4 v01 = *(const float4*)(pp + CSZ);
                const float4 v10 = *(const float4*)(pp + NSRC * CSZ);
                const float4 v11 = *(const float4*)(pp + NSRC * CSZ + CSZ);
                const float w00 = (1.0f - twy) * (1.0f - twx);
                const float w01 = (1.0f - twy) * twx;
                const float w10 = twy * (1.0f - twx);
                const float w11 = twy * twx;
                acc.x += w00 * v00.x + w01 * v01.x + w10 * v10.x + w11 * v11.x;
                acc.y += w00 * v00.y + w01 * v01.y + w10 * v10.y + w11 * v11.y;
                acc.z += w00 * v00.z + w01 * v01.z + w10 * v10.z + w11 * v11.z;
                acc.w += w00 * v00.w + w01 * v01.w + w10 * v10.w + w11 * v11.w;
            }
        }
    }

    smemO[c4o + 0][pi] = acc.x;
    smemO[c4o + 1][pi] = acc.y;
    smemO[c4o + 2][pi] = acc.z;
    smemO[c4o + 3][pi] = acc.w;
    __syncthreads();

    // --- phase 3: coalesced float4 stores (one per thread) ---
    {
        const int c   = t >> 2;          // 0..63
        const int px4 = (t & 3) * 4;     // 0..12
        float4 v;
        v.x = smemO[c][px4 + 0] * 0.0625f;
        v.y = smemO[c][px4 + 1] * 0.0625f;
        v.z = smemO[c][px4 + 2] * 0.0625f;
        v.w = smemO[c][px4 + 3] * 0.0625f;
        *(float4*)(out + (size_t)c * NPIX + p0 + px4) = v;
    }
}

extern "C" void kernel_launch(void* const* d_in, const int* in_sizes, int n_in,
                              void* d_out, int out_size, void* d_ws, size_t ws_size,
                              hipStream_t stream) {
    const float* src   = (const float*)d_in[0];
    const float* theta = (const float*)d_in[1];
    float* out = (float*)d_out;

    const size_t need = (size_t)CSZ * NSRC * NSRC * sizeof(float);  // 16.78 MB
    if (ws_size >= need) {
        float* ws = (float*)d_ws;
        transpose_kernel<<<dim3(NSRC * NSRC / 64), dim3(256), 0, stream>>>(src, ws);
        cubelens_main<<<dim3(NBLK), dim3(256), 0, stream>>>(ws, theta, out);
    } else {
        cubelens_fallback<<<dim3(NPIX / 256, 8), dim3(256), 0, stream>>>(src, theta, out);
    }
}